// Round 18
// baseline (220.781 us; speedup 1.0000x reference)
//
#include <hip/hip_runtime.h>
#include <stdint.h>

#define DEVI __device__ __forceinline__

typedef short bf16x8 __attribute__((ext_vector_type(8)));
typedef float f32x4  __attribute__((ext_vector_type(4)));

DEVI short f2bf(float f){
  union { float f; uint32_t u; } un; un.f = f;
  uint32_t u = un.u;
  u += 0x7fffu + ((u >> 16) & 1u);   // RNE
  return (short)(u >> 16);
}
DEVI float bf2f(uint32_t us){
  union { uint32_t u; float f; } x; x.u = us << 16; return x.f;
}

DEVI f32x4 mfma16(bf16x8 a, bf16x8 b, f32x4 c){
  return __builtin_amdgcn_mfma_f32_16x16x32_bf16(a, b, c, 0, 0, 0);
}

// ---------- merged prep: W1^T, W2^T (fp32->bf16 transpose) + hvb/ub ----------
__global__ __launch_bounds__(256) void prep_all(
    const float* __restrict__ W1, const float* __restrict__ W2,
    const float* __restrict__ hv, const float* __restrict__ V,
    const float* __restrict__ u,
    short* __restrict__ w1t, short* __restrict__ w2t,
    short* __restrict__ hvb, short* __restrict__ ub)
{
  const int bid = blockIdx.x;
  if (bid < 1280){
    const float* W = (bid < 1024) ? W1 : W2;
    short* WT      = (bid < 1024) ? w1t : w2t;
    const int R = 1024;
    const int C = (bid < 1024) ? 1024 : 256;
    const int b2 = (bid < 1024) ? bid : (bid - 1024);
    __shared__ float tile[32][33];
    int ctiles = C >> 5;
    int bi = b2 / ctiles, bj = b2 % ctiles;
    int tx = threadIdx.x & 31, ty = threadIdx.x >> 5;
    #pragma unroll
    for (int r = 0; r < 4; ++r){
      int i = bi*32 + ty + r*8;
      tile[ty + r*8][tx] = W[(size_t)i*C + bj*32 + tx];
    }
    __syncthreads();
    #pragma unroll
    for (int r = 0; r < 4; ++r){
      int j = bj*32 + ty + r*8;
      WT[(size_t)j*R + bi*32 + tx] = f2bf(tile[tx][ty + r*8]);
    }
  } else {
    int idx = (bid - 1280)*256 + threadIdx.x;
    if (idx < 512*256){
      int r = idx >> 8;
      hvb[idx] = f2bf(hv[idx] * V[r]);
    } else if (idx < 512*256 + 1024){
      int i2 = idx - 512*256;
      ub[i2] = f2bf(u[i2]);
    }
  }
}

// ---------- prep: s[(k,n)][j] = hv*W1[0:256] + u*W1[512:768] + b1   (bf16, row-major)
//                  tT[j][(k,m)] = hv*W1[256:512]                     (bf16, TRANSPOSED)
__global__ __launch_bounds__(256) void prep_st(
    const short* __restrict__ hvb, const short* __restrict__ ub,
    const short* __restrict__ w1t, const float* __restrict__ b1,
    short* __restrict__ sbuf, short* __restrict__ tbuf)
{
  const int bid = blockIdx.x;
  const int st = bid >> 7;           // 0 = s, 1 = t
  const int rt8 = (bid >> 4) & 7;    // 8 row tiles of 64 over 512 rows
  const int ctile = bid & 15;        // 16 col tiles of 64 over 1024 cols
  const int r0 = rt8 << 6, j0 = ctile << 6;
  const int tid = threadIdx.x;
  const int w = tid >> 6, l = tid & 63;
  const int l15 = l & 15, l4 = l >> 4;
  __shared__ short A[64*256];
  __shared__ short Stile[64][64];
  for (int q = 0; q < 8; ++q){
    int id = tid + (q << 8);
    int row = id >> 5, c8 = id & 31;
    bf16x8 v = *(const bf16x8*)(hvb + (size_t)(r0 + row)*256 + c8*8);
    *(bf16x8*)((char*)A + row*512 + ((c8*16) ^ ((row & 7) << 4))) = v;
  }
  __syncthreads();
  const int wr = w >> 1, wc = w & 1;
  const int rowbase = wr << 5, colbase = wc << 5;
  const int swzA = (l15 & 7) << 4;
  f32x4 acc[2][2];
  acc[0][0]=0; acc[0][1]=0; acc[1][0]=0; acc[1][1]=0;
  const int ioff = st ? 256 : 0;
  const short* w1p = w1t + (size_t)(j0 + colbase + l15)*1024 + ioff + l4*8;
  const char* ap0 = (const char*)A + (rowbase + l15)*512;
  const char* ap1 = ap0 + 16*512;
  #pragma unroll
  for (int kk = 0; kk < 8; ++kk){
    int ib = kk*64 + l4*16;
    bf16x8 a0 = *(const bf16x8*)(ap0 + (ib ^ swzA));
    bf16x8 a1 = *(const bf16x8*)(ap1 + (ib ^ swzA));
    bf16x8 b0 = *(const bf16x8*)(w1p + kk*32);
    bf16x8 b1v = *(const bf16x8*)(w1p + 16*1024 + kk*32);
    acc[0][0] = mfma16(a0, b0, acc[0][0]);
    acc[1][0] = mfma16(a1, b0, acc[1][0]);
    acc[0][1] = mfma16(a0, b1v, acc[0][1]);
    acc[1][1] = mfma16(a1, b1v, acc[1][1]);
  }
  if (st == 0){
    const int kb = r0 >> 7;
    const short* up = ub + kb*256 + l4*8;
    const short* w1pu = w1t + (size_t)(j0 + colbase + l15)*1024 + 512 + l4*8;
    #pragma unroll
    for (int kk = 0; kk < 8; ++kk){
      bf16x8 au = *(const bf16x8*)(up + kk*32);
      bf16x8 b0 = *(const bf16x8*)(w1pu + kk*32);
      bf16x8 b1v = *(const bf16x8*)(w1pu + 16*1024 + kk*32);
      acc[0][0] = mfma16(au, b0, acc[0][0]);
      acc[1][0] = mfma16(au, b0, acc[1][0]);
      acc[0][1] = mfma16(au, b1v, acc[0][1]);
      acc[1][1] = mfma16(au, b1v, acc[1][1]);
    }
  }
  #pragma unroll
  for (int r = 0; r < 2; ++r){
    #pragma unroll
    for (int c = 0; c < 2; ++c){
      int jl = colbase + c*16 + l15;
      float badd = st ? 0.f : b1[j0 + jl];
      #pragma unroll
      for (int reg = 0; reg < 4; ++reg){
        int rowl = rowbase + r*16 + l4*4 + reg;
        short v = f2bf(acc[r][c][reg] + badd);
        if (st == 0) Stile[rowl][jl] = v;
        else         Stile[jl][rowl] = v;
      }
    }
  }
  __syncthreads();
  {
    int a = tid >> 2, ch = (tid & 3) << 4;
    bf16x8 v0 = *(const bf16x8*)(&Stile[a][ch]);
    bf16x8 v1 = *(const bf16x8*)(&Stile[a][ch + 8]);
    short* dst = (st == 0)
      ? (sbuf + (size_t)(r0 + a)*1024 + j0 + ch)
      : (tbuf + (size_t)(j0 + a)*512  + r0 + ch);
    *(bf16x8*)(dst)     = v0;
    *(bf16x8*)(dst + 8) = v1;
  }
}

// ---------- main fused kernel: K-PAIR + low-register A-REUSE ----------
// R15 loop structure verbatim (8 phases BK=128, dbuf eluv, 1 barrier/phase)
// with ONE change: GEMM1 wave decomposition (128rows x 16cols) ->
// (64rows x 32cols): rowbase=(w&1)*64, cols (w>>1)*32. Each heb A-fragment
// feeds 2 MFMAs -> GEMM1 ds_reads HALVE (LDS unit ~40% of block wall).
// acc1 stays 4x2xf32x4 = 32 VGPR (R17's 64-VGPR acc1a/b spilled -> 181MB
// scratch WRITE; this version adds only +16 VGPR for the 2nd bw1 set).
// Cost: w1t L2 reads x2 (~+512KB/block ~ 1.6us) << LDS savings (~10us).
__global__ __launch_bounds__(512, 2) void fused_edge(
    const float* __restrict__ he, const unsigned short* __restrict__ sb,
    const unsigned short* __restrict__ tbT, const short* __restrict__ w1t,
    const short* __restrict__ w2t, const float* __restrict__ b2,
    const int* __restrict__ Em, float* __restrict__ out)
{
  const int bo = blockIdx.x;
  const int b = ((bo & 7) << 6) | (bo >> 3);   // XCD swizzle, bijective (512%8==0)
  const int kp = b >> 8;
  const int n  = (b >> 1) & 127;
  const int m0 = (b & 1) << 6;
  const int k0 = kp << 1;
  const int tid = threadIdx.x;
  const int w = tid >> 6, l = tid & 63;
  const int l15 = l & 15, l4 = l >> 4;

  __shared__ short heb[128*256];       // 64 KB  bf16 h_e (2 k's), XOR-swizzled
  __shared__ short eluv[2][128*128];   // 64 KB  dbuf ELU chunk
  __shared__ int   emask[128];

  const int base0 = (k0*128 + n)*128 + m0;

  // stage h_e -> bf16 LDS: 4096 chunks of 8, 8 per thread
  #pragma unroll
  for (int q = 0; q < 8; ++q){
    int id = tid + (q << 9);
    int row = id >> 5, c8 = id & 31;
    size_t grow = (size_t)base0 + (row >> 6)*16384 + (row & 63);
    const float4* p = (const float4*)(he + grow*256 + c8*8);
    float4 a4 = p[0], b4 = p[1];
    union { bf16x8 v; short s[8]; } pk;
    pk.s[0]=f2bf(a4.x); pk.s[1]=f2bf(a4.y); pk.s[2]=f2bf(a4.z); pk.s[3]=f2bf(a4.w);
    pk.s[4]=f2bf(b4.x); pk.s[5]=f2bf(b4.y); pk.s[6]=f2bf(b4.z); pk.s[7]=f2bf(b4.w);
    *(bf16x8*)((char*)heb + row*512 + ((c8*16) ^ ((row & 7) << 4))) = pk.v;
  }
  if (tid < 128)
    emask[tid] = Em[((size_t)base0 + (tid >> 6)*16384 + (tid & 63))*2 + 1];
  __syncthreads();

  f32x4 acc2[8][2];
  #pragma unroll
  for (int i = 0; i < 8; ++i){ acc2[i][0] = 0; acc2[i][1] = 0; }

  // GEMM1 ownership: rows rowbase..rowbase+63 (one k), cols colg..colg+31
  const int rowbase = (w & 1) << 6;          // 0 or 64
  const int colg    = (w >> 1) << 5;         // 0,32,64,96
  const int myk     = w & 1;                 // rows' k within the pair
  const unsigned short* srow = sb + (size_t)((k0 + myk)*128 + n)*1024;
  const int tcol = (k0 + myk)*128 + m0;      // tT col base for my rows
  const char* hb = (const char*)heb;
  const int swz = (l15 & 7) << 4;

  union u4 { ushort4 v; unsigned short s[4]; };

  // ---- prologue: loads for ph = 0 ----
  bf16x8 bw1a[8], bw1b[8];
  {
    const short* w1pa = w1t + (size_t)(colg + l15)*1024 + 768 + l4*8;
    #pragma unroll
    for (int kk = 0; kk < 8; ++kk){
      bw1a[kk] = *(const bf16x8*)(w1pa + kk*32);
      bw1b[kk] = *(const bf16x8*)(w1pa + 16*1024 + kk*32);
    }
  }
  u4 t4a[4], t4b[4];
  #pragma unroll
  for (int rt = 0; rt < 4; ++rt){
    t4a[rt].v = *(const ushort4*)(tbT + (size_t)(colg + l15)*512      + tcol + rt*16 + l4*4);
    t4b[rt].v = *(const ushort4*)(tbT + (size_t)(colg + 16 + l15)*512 + tcol + rt*16 + l4*4);
  }
  float sva = bf2f(srow[colg + l15]);
  float svb = bf2f(srow[colg + 16 + l15]);

  for (int ph = 0; ph < 8; ++ph){
    const int jca = ph*128 + colg + l15;     // group-a hidden col

    // ---- GEMM1: z1[64(rows) x 32(cols)] -- each A-read feeds 2 MFMAs ----
    f32x4 acc1[4][2];
    #pragma unroll
    for (int i = 0; i < 4; ++i){ acc1[i][0] = 0; acc1[i][1] = 0; }
    #pragma unroll
    for (int kk = 0; kk < 8; ++kk){
      int ib = kk*64 + l4*16;
      bf16x8 ba = bw1a[kk], bb = bw1b[kk];
      #pragma unroll
      for (int rt = 0; rt < 4; ++rt){
        int row = rowbase + rt*16 + l15;
        bf16x8 a = *(const bf16x8*)(hb + row*512 + (ib ^ swz));
        acc1[rt][0] = mfma16(a, ba, acc1[rt][0]);
        acc1[rt][1] = mfma16(a, bb, acc1[rt][1]);
      }
    }

    // ---- issue all W2 fragments for this phase (consumed after barrier) ----
    const short* w2p = w2t + (size_t)(w*32 + l15)*1024 + ph*128 + l4*8;
    bf16x8 bw2[2][4];
    #pragma unroll
    for (int ct = 0; ct < 2; ++ct)
      #pragma unroll
      for (int kk = 0; kk < 4; ++kk)
        bw2[ct][kk] = *(const bf16x8*)(w2p + (size_t)ct*16*1024 + kk*32);

    // ---- reload bw1 for ph+1 (regs dead after GEMM1) ----
    if (ph < 7){
      const short* w1pa = w1t + (size_t)(jca + 128)*1024 + 768 + l4*8;
      #pragma unroll
      for (int kk = 0; kk < 8; ++kk){
        bw1a[kk] = *(const bf16x8*)(w1pa + kk*32);
        bw1b[kk] = *(const bf16x8*)(w1pa + 16*1024 + kk*32);
      }
    }

    // ---- ELU: z1 + s + t -> bf16 LDS dbuf (rows rowbase..+63, cols colg..+31) ----
    char* eb = (char*)(&eluv[ph & 1][0]);
    const int cba = (colg + l15)*2;
    #pragma unroll
    for (int rt = 0; rt < 4; ++rt){
      #pragma unroll
      for (int reg = 0; reg < 4; ++reg){
        int row = rowbase + rt*16 + l4*4 + reg;
        int sw = (row & 7) << 4;
        float va = acc1[rt][0][reg] + sva + bf2f(t4a[rt].s[reg]);
        float vb = acc1[rt][1][reg] + svb + bf2f(t4b[rt].s[reg]);
        va = va > 0.f ? va : (__expf(va) - 1.f);
        vb = vb > 0.f ? vb : (__expf(vb) - 1.f);
        *(short*)(eb + row*256 + (cba ^ sw))        = f2bf(va);
        *(short*)(eb + row*256 + ((cba + 32) ^ sw)) = f2bf(vb);
      }
    }

    // ---- prefetch t4/sv for ph+1 (R11-proven position) ----
    if (ph < 7){
      #pragma unroll
      for (int rt = 0; rt < 4; ++rt){
        t4a[rt].v = *(const ushort4*)(tbT + (size_t)(jca + 128)*512      + tcol + rt*16 + l4*4);
        t4b[rt].v = *(const ushort4*)(tbT + (size_t)(jca + 16 + 128)*512 + tcol + rt*16 + l4*4);
      }
      sva = bf2f(srow[jca + 128]);
      svb = bf2f(srow[jca + 16 + 128]);
    }
    __syncthreads();   // eluv[ph&1] ready (1 barrier/phase; dbuf + wave-skew bound)

    // ---- GEMM2: acc2 += ELU-chunk[128 x 128] @ W2[ph*128:+128, w*32:+32] ----
    #pragma unroll
    for (int kk = 0; kk < 4; ++kk){
      int jb = kk*64 + l4*16;
      #pragma unroll
      for (int rt = 0; rt < 8; ++rt){
        int row = rt*16 + l15;
        bf16x8 a2 = *(const bf16x8*)(eb + row*256 + (jb ^ ((row & 7) << 4)));
        acc2[rt][0] = mfma16(a2, bw2[0][kk], acc2[rt][0]);
        acc2[rt][1] = mfma16(a2, bw2[1][kk], acc2[rt][1]);
      }
    }
  }

  // ---- epilogue: + b2, E-mask, residual from LDS heb (bf16), store ----
  const float bias0 = b2[w*32 + l15];
  const float bias1 = b2[w*32 + 16 + l15];
  #pragma unroll
  for (int rt = 0; rt < 8; ++rt){
    #pragma unroll
    for (int reg = 0; reg < 4; ++reg){
      int row = rt*16 + l4*4 + reg;
      int e = emask[row];
      size_t grow = (size_t)base0 + (row >> 6)*16384 + (row & 63);
      float* op = out + grow*256 + w*32 + l15;
      const char* hrow = hb + row*512;
      int sw = (row & 7) << 4;
      float hv0 = bf2f(*(const unsigned short*)(hrow + (((w*32 + l15)*2) ^ sw)));
      float hv1 = bf2f(*(const unsigned short*)(hrow + (((w*32 + 16 + l15)*2) ^ sw)));
      op[0]  = ((e == 1) ? (acc2[rt][0][reg] + bias0) : 0.f) + hv0;
      op[16] = ((e == 1) ? (acc2[rt][1][reg] + bias1) : 0.f) + hv1;
    }
  }
}

extern "C" void kernel_launch(void* const* d_in, const int* in_sizes, int n_in,
                              void* d_out, int out_size, void* d_ws, size_t ws_size,
                              hipStream_t stream)
{
  const float* u   = (const float*)d_in[0];
  const float* h_v = (const float*)d_in[1];
  const float* h_e = (const float*)d_in[2];
  const float* V   = (const float*)d_in[3];
  const int*   E   = (const int*)d_in[4];
  const float* W1  = (const float*)d_in[5];
  const float* b1  = (const float*)d_in[6];
  const float* W2  = (const float*)d_in[7];
  const float* b2  = (const float*)d_in[8];
  float* out = (float*)d_out;

  char* ws = (char*)d_ws;
  short* w1t  = (short*)(ws);                               // 2 MB   bf16 W1^T [1024][1024]
  short* w2t  = (short*)(ws + (2u<<20));                    // 512KB  bf16 W2^T [256][1024]
  short* hvb  = (short*)(ws + (2u<<20) + (512u<<10));       // 256KB  bf16 masked h_v
  short* ub   = (short*)(ws + (2u<<20) + (768u<<10));       // 2KB    bf16 u
  short* sbuf = (short*)(ws + (3u<<20));                    // 1 MB   bf16 s [512][1024]
  short* tbuf = (short*)(ws + (4u<<20));                    // 1 MB   bf16 tT [1024][512]

  prep_all<<<1796, 256, 0, stream>>>(W1, W2, h_v, V, u, w1t, w2t, hvb, ub);
  prep_st<<<256, 256, 0, stream>>>(hvb, ub, w1t, b1, sbuf, tbuf);
  fused_edge<<<512, 512, 0, stream>>>(h_e,
                                      (const unsigned short*)sbuf,
                                      (const unsigned short*)tbuf,
                                      w1t, w2t, b2, E, out);
}

// Round 19
// 177.019 us; speedup vs baseline: 1.2472x; 1.2472x over previous
//
#include <hip/hip_runtime.h>
#include <stdint.h>

#define DEVI __device__ __forceinline__

typedef short bf16x8 __attribute__((ext_vector_type(8)));
typedef float f32x4  __attribute__((ext_vector_type(4)));

DEVI short f2bf(float f){
  union { float f; uint32_t u; } un; un.f = f;
  uint32_t u = un.u;
  u += 0x7fffu + ((u >> 16) & 1u);   // RNE
  return (short)(u >> 16);
}
DEVI float bf2f(uint32_t us){
  union { uint32_t u; float f; } x; x.u = us << 16; return x.f;
}

DEVI f32x4 mfma16(bf16x8 a, bf16x8 b, f32x4 c){
  return __builtin_amdgcn_mfma_f32_16x16x32_bf16(a, b, c, 0, 0, 0);
}

// ---------- merged prep: W1^T, W2^T (fp32->bf16 transpose) + hvb/ub ----------
// blocks 0..1023   : transpose W1 [1024][1024] -> w1t [1024][1024]
// blocks 1024..1279: transpose W2 [1024][256]  -> w2t [256][1024]
// blocks 1280..1795: hvb = bf16(h_v * V), ub = bf16(u)
__global__ __launch_bounds__(256) void prep_all(
    const float* __restrict__ W1, const float* __restrict__ W2,
    const float* __restrict__ hv, const float* __restrict__ V,
    const float* __restrict__ u,
    short* __restrict__ w1t, short* __restrict__ w2t,
    short* __restrict__ hvb, short* __restrict__ ub)
{
  const int bid = blockIdx.x;
  if (bid < 1280){
    const float* W = (bid < 1024) ? W1 : W2;
    short* WT      = (bid < 1024) ? w1t : w2t;
    const int R = 1024;
    const int C = (bid < 1024) ? 1024 : 256;
    const int b2 = (bid < 1024) ? bid : (bid - 1024);
    __shared__ float tile[32][33];
    int ctiles = C >> 5;
    int bi = b2 / ctiles, bj = b2 % ctiles;
    int tx = threadIdx.x & 31, ty = threadIdx.x >> 5;
    #pragma unroll
    for (int r = 0; r < 4; ++r){
      int i = bi*32 + ty + r*8;
      tile[ty + r*8][tx] = W[(size_t)i*C + bj*32 + tx];
    }
    __syncthreads();
    #pragma unroll
    for (int r = 0; r < 4; ++r){
      int j = bj*32 + ty + r*8;
      WT[(size_t)j*R + bi*32 + tx] = f2bf(tile[tx][ty + r*8]);
    }
  } else {
    int idx = (bid - 1280)*256 + threadIdx.x;
    if (idx < 512*256){
      int r = idx >> 8;
      hvb[idx] = f2bf(hv[idx] * V[r]);
    } else if (idx < 512*256 + 1024){
      int i2 = idx - 512*256;
      ub[i2] = f2bf(u[i2]);
    }
  }
}

// ---------- prep: s[(k,n)][j] = hv*W1[0:256] + u*W1[512:768] + b1   (bf16, row-major)
//                  tT[j][(k,m)] = hv*W1[256:512]                     (bf16, TRANSPOSED)
__global__ __launch_bounds__(256) void prep_st(
    const short* __restrict__ hvb, const short* __restrict__ ub,
    const short* __restrict__ w1t, const float* __restrict__ b1,
    short* __restrict__ sbuf, short* __restrict__ tbuf)
{
  const int bid = blockIdx.x;
  const int st = bid >> 7;           // 0 = s, 1 = t
  const int rt8 = (bid >> 4) & 7;    // 8 row tiles of 64 over 512 rows
  const int ctile = bid & 15;        // 16 col tiles of 64 over 1024 cols
  const int r0 = rt8 << 6, j0 = ctile << 6;
  const int tid = threadIdx.x;
  const int w = tid >> 6, l = tid & 63;
  const int l15 = l & 15, l4 = l >> 4;
  __shared__ short A[64*256];
  __shared__ short Stile[64][64];
  for (int q = 0; q < 8; ++q){
    int id = tid + (q << 8);
    int row = id >> 5, c8 = id & 31;
    bf16x8 v = *(const bf16x8*)(hvb + (size_t)(r0 + row)*256 + c8*8);
    *(bf16x8*)((char*)A + row*512 + ((c8*16) ^ ((row & 7) << 4))) = v;
  }
  __syncthreads();
  const int wr = w >> 1, wc = w & 1;
  const int rowbase = wr << 5, colbase = wc << 5;
  const int swzA = (l15 & 7) << 4;
  f32x4 acc[2][2];
  acc[0][0]=0; acc[0][1]=0; acc[1][0]=0; acc[1][1]=0;
  const int ioff = st ? 256 : 0;
  const short* w1p = w1t + (size_t)(j0 + colbase + l15)*1024 + ioff + l4*8;
  const char* ap0 = (const char*)A + (rowbase + l15)*512;
  const char* ap1 = ap0 + 16*512;
  #pragma unroll
  for (int kk = 0; kk < 8; ++kk){
    int ib = kk*64 + l4*16;
    bf16x8 a0 = *(const bf16x8*)(ap0 + (ib ^ swzA));
    bf16x8 a1 = *(const bf16x8*)(ap1 + (ib ^ swzA));
    bf16x8 b0 = *(const bf16x8*)(w1p + kk*32);
    bf16x8 b1v = *(const bf16x8*)(w1p + 16*1024 + kk*32);
    acc[0][0] = mfma16(a0, b0, acc[0][0]);
    acc[1][0] = mfma16(a1, b0, acc[1][0]);
    acc[0][1] = mfma16(a0, b1v, acc[0][1]);
    acc[1][1] = mfma16(a1, b1v, acc[1][1]);
  }
  if (st == 0){
    const int kb = r0 >> 7;
    const short* up = ub + kb*256 + l4*8;
    const short* w1pu = w1t + (size_t)(j0 + colbase + l15)*1024 + 512 + l4*8;
    #pragma unroll
    for (int kk = 0; kk < 8; ++kk){
      bf16x8 au = *(const bf16x8*)(up + kk*32);
      bf16x8 b0 = *(const bf16x8*)(w1pu + kk*32);
      bf16x8 b1v = *(const bf16x8*)(w1pu + 16*1024 + kk*32);
      acc[0][0] = mfma16(au, b0, acc[0][0]);
      acc[1][0] = mfma16(au, b0, acc[1][0]);
      acc[0][1] = mfma16(au, b1v, acc[0][1]);
      acc[1][1] = mfma16(au, b1v, acc[1][1]);
    }
  }
  #pragma unroll
  for (int r = 0; r < 2; ++r){
    #pragma unroll
    for (int c = 0; c < 2; ++c){
      int jl = colbase + c*16 + l15;
      float badd = st ? 0.f : b1[j0 + jl];
      #pragma unroll
      for (int reg = 0; reg < 4; ++reg){
        int rowl = rowbase + r*16 + l4*4 + reg;
        short v = f2bf(acc[r][c][reg] + badd);
        if (st == 0) Stile[rowl][jl] = v;
        else         Stile[jl][rowl] = v;
      }
    }
  }
  __syncthreads();
  {
    int a = tid >> 2, ch = (tid & 3) << 4;
    bf16x8 v0 = *(const bf16x8*)(&Stile[a][ch]);
    bf16x8 v1 = *(const bf16x8*)(&Stile[a][ch + 8]);
    short* dst = (st == 0)
      ? (sbuf + (size_t)(r0 + a)*1024 + j0 + ch)
      : (tbuf + (size_t)(j0 + a)*512  + r0 + ch);
    *(bf16x8*)(dst)     = v0;
    *(bf16x8*)(dst + 8) = v1;
  }
}

// ---------- main fused kernel: K-PAIR structure (R15/R16 verbatim — BEST) ----------
// block = (kp, n, m-half): TWO batch k's x 64 m-rows = 128 rows; 512 blocks x
// 8 waves; weights shared across the k-pair (halved load:MFMA ratio + barriers).
// One barrier per phase (dbuf eluv, race-free by wave-skew transitivity).
// FINAL LEDGER (18 rounds): 307 -> 177us via K-pair amortization (R11, +14%),
// occupancy/spill fixes (R5/R8), coalesced prep (R8), prep merge (R16, -4us).
// Every scheduling tweak on this lockstep structure measured NEGATIVE:
// eluv re-swizzles (+14..26us), setprio (+), LDS-bounce epilogue (+), early
// t4-prefetch staging (+18us), A-reuse geometries x3 (+26..43us: spills or
// issue-latency serialization). SQ_LDS_BANK_CONFLICT ~8-12M = counted-but-free
// 2-way merges. Kernel is issue-latency-bound at 2 waves/SIMD; further gains
// need counted-vmcnt asm pipeline whose prereqs this structure can't meet.
__global__ __launch_bounds__(512, 2) void fused_edge(
    const float* __restrict__ he, const unsigned short* __restrict__ sb,
    const unsigned short* __restrict__ tbT, const short* __restrict__ w1t,
    const short* __restrict__ w2t, const float* __restrict__ b2,
    const int* __restrict__ Em, float* __restrict__ out)
{
  const int bo = blockIdx.x;
  const int b = ((bo & 7) << 6) | (bo >> 3);   // XCD swizzle, bijective (512%8==0)
  const int kp = b >> 8;
  const int n  = (b >> 1) & 127;
  const int m0 = (b & 1) << 6;
  const int k0 = kp << 1;
  const int tid = threadIdx.x;
  const int w = tid >> 6, l = tid & 63;
  const int l15 = l & 15, l4 = l >> 4;

  __shared__ short heb[128*256];       // 64 KB  bf16 h_e (2 k's), XOR-swizzled
  __shared__ short eluv[2][128*128];   // 64 KB  dbuf ELU chunk
  __shared__ int   emask[128];

  const int base0 = (k0*128 + n)*128 + m0;

  // stage h_e -> bf16 LDS: 4096 chunks of 8, 8 per thread
  #pragma unroll
  for (int q = 0; q < 8; ++q){
    int id = tid + (q << 9);
    int row = id >> 5, c8 = id & 31;
    size_t grow = (size_t)base0 + (row >> 6)*16384 + (row & 63);
    const float4* p = (const float4*)(he + grow*256 + c8*8);
    float4 a4 = p[0], b4 = p[1];
    union { bf16x8 v; short s[8]; } pk;
    pk.s[0]=f2bf(a4.x); pk.s[1]=f2bf(a4.y); pk.s[2]=f2bf(a4.z); pk.s[3]=f2bf(a4.w);
    pk.s[4]=f2bf(b4.x); pk.s[5]=f2bf(b4.y); pk.s[6]=f2bf(b4.z); pk.s[7]=f2bf(b4.w);
    *(bf16x8*)((char*)heb + row*512 + ((c8*16) ^ ((row & 7) << 4))) = pk.v;
  }
  if (tid < 128)
    emask[tid] = Em[((size_t)base0 + (tid >> 6)*16384 + (tid & 63))*2 + 1];
  __syncthreads();

  f32x4 acc2[8][2];
  #pragma unroll
  for (int i = 0; i < 8; ++i){ acc2[i][0] = 0; acc2[i][1] = 0; }

  const unsigned short* srow0 = sb + (size_t)(k0*128 + n)*1024;
  const unsigned short* srow1 = srow0 + 128*1024;
  const int tcol0 = k0*128 + m0;
  const int tcol1 = tcol0 + 128;
  const char* hb = (const char*)heb;
  const int swz = (l15 & 7) << 4;

  union u4 { ushort4 v; unsigned short s[4]; };

  // ---- prologue: loads for ph = 0 ----
  bf16x8 bw1[8];
  {
    const short* w1p = w1t + (size_t)(w*16 + l15)*1024 + 768 + l4*8;
    #pragma unroll
    for (int kk = 0; kk < 8; ++kk) bw1[kk] = *(const bf16x8*)(w1p + kk*32);
  }
  u4 t4[8];
  #pragma unroll
  for (int rt = 0; rt < 8; ++rt){
    int tc = (rt < 4) ? (tcol0 + rt*16) : (tcol1 + (rt - 4)*16);
    t4[rt].v = *(const ushort4*)(tbT + (size_t)(w*16 + l15)*512 + tc + l4*4);
  }
  float sv0 = bf2f(srow0[w*16 + l15]);
  float sv1 = bf2f(srow1[w*16 + l15]);

  for (int ph = 0; ph < 8; ++ph){
    const int jcol = ph*128 + w*16 + l15;

    // ---- GEMM1: z1[128 x 16(w)] = heb @ W1[768:1024, jcol] ----
    f32x4 acc1[8];
    #pragma unroll
    for (int i = 0; i < 8; ++i) acc1[i] = 0;
    #pragma unroll
    for (int kk = 0; kk < 8; ++kk){
      int ib = kk*64 + l4*16;
      #pragma unroll
      for (int rt = 0; rt < 8; ++rt){
        int row = rt*16 + l15;
        bf16x8 a = *(const bf16x8*)(hb + row*512 + (ib ^ swz));
        acc1[rt] = mfma16(a, bw1[kk], acc1[rt]);
      }
    }

    // ---- issue all W2 fragments for this phase (consumed after barrier) ----
    const short* w2p = w2t + (size_t)(w*32 + l15)*1024 + ph*128 + l4*8;
    bf16x8 bw2[2][4];
    #pragma unroll
    for (int ct = 0; ct < 2; ++ct)
      #pragma unroll
      for (int kk = 0; kk < 4; ++kk)
        bw2[ct][kk] = *(const bf16x8*)(w2p + (size_t)ct*16*1024 + kk*32);

    // ---- reload bw1 for ph+1 (regs dead after GEMM1) ----
    if (ph < 7){
      const short* w1p = w1t + (size_t)(jcol + 128)*1024 + 768 + l4*8;
      #pragma unroll
      for (int kk = 0; kk < 8; ++kk) bw1[kk] = *(const bf16x8*)(w1p + kk*32);
    }

    // ---- ELU: z1 + s + t -> bf16 LDS dbuf (swizzled; 2-way merge = free) ----
    char* eb = (char*)(&eluv[ph & 1][0]);
    const int cb = (w*16 + l15)*2;
    #pragma unroll
    for (int rt = 0; rt < 8; ++rt){
      float sv = (rt < 4) ? sv0 : sv1;
      #pragma unroll
      for (int reg = 0; reg < 4; ++reg){
        int row = rt*16 + l4*4 + reg;
        float v = acc1[rt][reg] + sv + bf2f(t4[rt].s[reg]);
        v = v > 0.f ? v : (__expf(v) - 1.f);
        *(short*)(eb + row*256 + (cb ^ ((row & 7) << 4))) = f2bf(v);
      }
    }

    // ---- prefetch t4/sv for ph+1 ----
    if (ph < 7){
      #pragma unroll
      for (int rt = 0; rt < 8; ++rt){
        int tc = (rt < 4) ? (tcol0 + rt*16) : (tcol1 + (rt - 4)*16);
        t4[rt].v = *(const ushort4*)(tbT + (size_t)(jcol + 128)*512 + tc + l4*4);
      }
      sv0 = bf2f(srow0[jcol + 128]);
      sv1 = bf2f(srow1[jcol + 128]);
    }
    __syncthreads();   // eluv[ph&1] ready (1 barrier/phase; dbuf + wave-skew bound)

    // ---- GEMM2: acc2 += ELU-chunk @ W2[ph*128:+128, w*32:+32] ----
    #pragma unroll
    for (int kk = 0; kk < 4; ++kk){
      int jb = kk*64 + l4*16;
      #pragma unroll
      for (int rt = 0; rt < 8; ++rt){
        int row = rt*16 + l15;
        bf16x8 a2 = *(const bf16x8*)(eb + row*256 + (jb ^ ((row & 7) << 4)));
        acc2[rt][0] = mfma16(a2, bw2[0][kk], acc2[rt][0]);
        acc2[rt][1] = mfma16(a2, bw2[1][kk], acc2[rt][1]);
      }
    }
  }

  // ---- epilogue: + b2, E-mask, residual from LDS heb (bf16), store ----
  const float bias0 = b2[w*32 + l15];
  const float bias1 = b2[w*32 + 16 + l15];
  #pragma unroll
  for (int rt = 0; rt < 8; ++rt){
    #pragma unroll
    for (int reg = 0; reg < 4; ++reg){
      int row = rt*16 + l4*4 + reg;
      int e = emask[row];
      size_t grow = (size_t)base0 + (row >> 6)*16384 + (row & 63);
      float* op = out + grow*256 + w*32 + l15;
      const char* hrow = hb + row*512;
      int sw = (row & 7) << 4;
      float hv0 = bf2f(*(const unsigned short*)(hrow + (((w*32 + l15)*2) ^ sw)));
      float hv1 = bf2f(*(const unsigned short*)(hrow + (((w*32 + 16 + l15)*2) ^ sw)));
      op[0]  = ((e == 1) ? (acc2[rt][0][reg] + bias0) : 0.f) + hv0;
      op[16] = ((e == 1) ? (acc2[rt][1][reg] + bias1) : 0.f) + hv1;
    }
  }
}

extern "C" void kernel_launch(void* const* d_in, const int* in_sizes, int n_in,
                              void* d_out, int out_size, void* d_ws, size_t ws_size,
                              hipStream_t stream)
{
  const float* u   = (const float*)d_in[0];
  const float* h_v = (const float*)d_in[1];
  const float* h_e = (const float*)d_in[2];
  const float* V   = (const float*)d_in[3];
  const int*   E   = (const int*)d_in[4];
  const float* W1  = (const float*)d_in[5];
  const float* b1  = (const float*)d_in[6];
  const float* W2  = (const float*)d_in[7];
  const float* b2  = (const float*)d_in[8];
  float* out = (float*)d_out;

  char* ws = (char*)d_ws;
  short* w1t  = (short*)(ws);                               // 2 MB   bf16 W1^T [1024][1024]
  short* w2t  = (short*)(ws + (2u<<20));                    // 512KB  bf16 W2^T [256][1024]
  short* hvb  = (short*)(ws + (2u<<20) + (512u<<10));       // 256KB  bf16 masked h_v
  short* ub   = (short*)(ws + (2u<<20) + (768u<<10));       // 2KB    bf16 u
  short* sbuf = (short*)(ws + (3u<<20));                    // 1 MB   bf16 s [512][1024]
  short* tbuf = (short*)(ws + (4u<<20));                    // 1 MB   bf16 tT [1024][512]

  prep_all<<<1796, 256, 0, stream>>>(W1, W2, h_v, V, u, w1t, w2t, hvb, ub);
  prep_st<<<256, 256, 0, stream>>>(hvb, ub, w1t, b1, sbuf, tbuf);
  fused_edge<<<512, 512, 0, stream>>>(h_e,
                                      (const unsigned short*)sbuf,
                                      (const unsigned short*)tbuf,
                                      w1t, w2t, b2, E, out);
}